// Round 3
// baseline (475.162 us; speedup 1.0000x reference)
//
#include <hip/hip_runtime.h>

typedef unsigned short u16;
typedef __attribute__((ext_vector_type(4))) float f32x4;
typedef __attribute__((ext_vector_type(8))) __bf16 bf16x8;

static __device__ __forceinline__ u16 f2bf(float f) {
  unsigned u = __float_as_uint(f);
  u += 0x7FFFu + ((u >> 16) & 1u);
  return (u16)(u >> 16);
}
static __device__ __forceinline__ float bf2f(u16 h) {
  return __uint_as_float(((unsigned)h) << 16);
}

#define GLOAD16(gsrc, ldst)                                                    \
  __builtin_amdgcn_global_load_lds(                                            \
      (const __attribute__((address_space(1))) unsigned int*)(gsrc),           \
      (__attribute__((address_space(3))) unsigned int*)(ldst), 16, 0, 0)

// ---------------- f32 -> bf16 convert (vectorized) ----------------
__global__ void k_cvt_bf16(const float* __restrict__ in, u16* __restrict__ out, int n4) {
  int i = blockIdx.x * blockDim.x + threadIdx.x;
  if (i >= n4) return;
  float4 v = ((const float4*)in)[i];
  ushort4 o;
  o.x = f2bf(v.x); o.y = f2bf(v.y); o.z = f2bf(v.z); o.w = f2bf(v.w);
  ((ushort4*)out)[i] = o;
}

// ---------------- GEMM: C[M,N] = A[M,K] @ Bt[N,K]^T + bias ----------------
// A, Bt bf16 row-major. M%128==0, N%128==0, K%32==0.
// 128x128 tile, BK=32, 4 waves (2x2 of 64x64), mfma 16x16x32 bf16.
// LDS staged via global_load_lds w=16; chunk XOR swizzle (c ^ (row&3)) applied
// on the GLOBAL source and on the ds_read side (both-sides rule).
template <int OUT_F32>
__global__ __launch_bounds__(256) void k_gemm_bt(const u16* __restrict__ A,
                                                 const u16* __restrict__ Bt,
                                                 const float* __restrict__ bias,
                                                 void* __restrict__ Cv,
                                                 int M, int N, int K) {
  __shared__ __align__(128) char smem[16384];
  const int tid = threadIdx.x;
  const int lane = tid & 63;
  const int wave = tid >> 6;
  const int m0 = blockIdx.y << 7;
  const int n0 = blockIdx.x << 7;
  const int wr = (wave >> 1) << 6;
  const int wc = (wave & 1) << 6;

  f32x4 acc[4][4];
#pragma unroll
  for (int m = 0; m < 4; ++m)
#pragma unroll
    for (int n = 0; n < 4; ++n) acc[m][n] = (f32x4){0.f, 0.f, 0.f, 0.f};

  const int nk = K >> 5;
  for (int kt = 0; kt < nk; ++kt) {
    const int kk0 = kt << 5;
#pragma unroll
    for (int iss = 0; iss < 4; ++iss) {
      int o = tid * 16 + iss * 4096;   // linear LDS byte this lane fills
      int lo = o & 8191;
      int row = lo >> 6;               // tile row (64B per row of 32 bf16)
      int cs = ((lo >> 4) & 3) ^ (row & 3);  // source chunk (inverse swizzle)
      const u16* src =
          (o >= 8192 ? Bt + (size_t)(n0 + row) * K : A + (size_t)(m0 + row) * K) + kk0 + cs * 8;
      GLOAD16(src, smem + iss * 4096 + wave * 1024);
    }
    __syncthreads();
    bf16x8 af[4], bfr[4];
#pragma unroll
    for (int m = 0; m < 4; ++m) {
      int r = wr + m * 16 + (lane & 15);
      af[m] = *(const bf16x8*)(smem + r * 64 + (((lane >> 4) ^ (r & 3)) << 4));
    }
#pragma unroll
    for (int n = 0; n < 4; ++n) {
      int r = wc + n * 16 + (lane & 15);
      bfr[n] = *(const bf16x8*)(smem + 8192 + r * 64 + (((lane >> 4) ^ (r & 3)) << 4));
    }
#pragma unroll
    for (int m = 0; m < 4; ++m)
#pragma unroll
      for (int n = 0; n < 4; ++n)
        acc[m][n] = __builtin_amdgcn_mfma_f32_16x16x32_bf16(af[m], bfr[n], acc[m][n], 0, 0, 0);
    __syncthreads();
  }

  // epilogue: D row = (lane>>4)*4 + j, col = lane&15  [m89-verified layout]
#pragma unroll
  for (int n = 0; n < 4; ++n) {
    int col = n0 + wc + n * 16 + (lane & 15);
    float bsv = bias[col];
#pragma unroll
    for (int m = 0; m < 4; ++m) {
      int rb = m0 + wr + m * 16 + ((lane >> 4) << 2);
#pragma unroll
      for (int j = 0; j < 4; ++j) {
        float v = acc[m][n][j] + bsv;
        if (OUT_F32)
          ((float*)Cv)[(size_t)(rb + j) * N + col] = v;
        else
          ((u16*)Cv)[(size_t)(rb + j) * N + col] = f2bf(v);
      }
    }
  }
}

// ---------------- RoPE (in place on QKV buffer), folds 1/sqrt(DH) into Q ----
// QKV layout: [4096 rows][3072]: Q cols h*128+d (h<16), K cols 2048+g*128+d,
// V cols 2560+g*128+d. One thread per (row, head, pair).
__global__ void k_rope(u16* __restrict__ qkv) {
  int t = blockIdx.x * blockDim.x + threadIdx.x;  // 4096*1280 exact
  int row = t / 1280;
  int p = t - row * 1280;
  int head = p >> 6;  // 0..15 Q heads, 16..19 K heads
  int i = p & 63;
  int s = row & 2047;
  int col = head < 16 ? (head << 7) + (i << 1) : 2048 + ((head - 16) << 7) + (i << 1);
  u16* ptr = qkv + (size_t)row * 3072 + col;
  ushort2 xv = *(ushort2*)ptr;
  float xe = bf2f(xv.x), xo = bf2f(xv.y);
  float omega = __expf(-0.21586735f * (float)i);  // exp(-2i/128 * ln 1e6)
  float ang = (float)s * omega;
  float sn, cs;
  sincosf(ang, &sn, &cs);
  float re = xe * cs - xo * sn;
  float ro = xo * cs + xe * sn;
  if (head < 16) { re *= 0.08838834764831845f; ro *= 0.08838834764831845f; }
  ushort2 ov;
  ov.x = f2bf(re); ov.y = f2bf(ro);
  *(ushort2*)ptr = ov;
}

// ---------------- causal GQA flash attention ----------------
// grid: (32 q-tiles of 64 rows, 32 = B*H). 4 waves x 16 q-rows each.
// K/V tiles 32x128 in LDS (XOR swizzle c^(r&7)); P via per-wave LDS roundtrip.
__global__ __launch_bounds__(256) void k_attn(const u16* __restrict__ qkv,
                                              u16* __restrict__ Ob) {
  __shared__ __align__(128) char smem[20480];  // K 8K | V 8K | P 4x1K
  const int tid = threadIdx.x, lane = tid & 63, wave = tid >> 6;
  const int Q0 = blockIdx.x << 6;
  const int bh = blockIdx.y;
  const int b = bh >> 4, h = bh & 15, g = h >> 2;
  const int brow = b << 11;
  const int qcol = h << 7;
  const int kcol = 2048 + (g << 7);
  const int vcol = 2560 + (g << 7);

  // Q A-fragments: row = lane&15, k(=d) = (lane>>4)*8 + j, per 32-wide chunk kk
  bf16x8 qf[4];
  {
    int qrow = brow + Q0 + wave * 16 + (lane & 15);
    const u16* qp = qkv + (size_t)qrow * 3072 + qcol + ((lane >> 4) << 3);
#pragma unroll
    for (int kk = 0; kk < 4; ++kk) qf[kk] = *(const bf16x8*)(qp + kk * 32);
  }

  f32x4 oacc[8];
#pragma unroll
  for (int d = 0; d < 8; ++d) oacc[d] = (f32x4){0.f, 0.f, 0.f, 0.f};
  float mrow[4], lrow[4];
#pragma unroll
  for (int j = 0; j < 4; ++j) { mrow[j] = -1e30f; lrow[j] = 0.f; }

  const int qmaxw = Q0 + wave * 16 + 15;
  const int nkt = (Q0 >> 5) + 2;

  for (int kt = 0; kt < nkt; ++kt) {
    // stage K (issues 0,1) and V (issues 2,3): 32 rows x 256B each
#pragma unroll
    for (int iss = 0; iss < 4; ++iss) {
      int o = tid * 16 + iss * 4096;
      int lo = o & 8191;
      int row = lo >> 8;
      int cs = ((lo >> 4) & 15) ^ (row & 7);
      const u16* src = qkv + (size_t)(brow + kt * 32 + row) * 3072 +
                       (o >= 8192 ? vcol : kcol) + cs * 8;
      GLOAD16(src, smem + iss * 4096 + wave * 1024);
    }
    __syncthreads();

    if ((kt << 5) <= qmaxw) {
      // ---- QK^T: S[16q x 32k], two 16-col fragments ----
      f32x4 sfr[2];
#pragma unroll
      for (int kc = 0; kc < 2; ++kc) {
        f32x4 s = (f32x4){0.f, 0.f, 0.f, 0.f};
        int r = kc * 16 + (lane & 15);
#pragma unroll
        for (int kk = 0; kk < 4; ++kk) {
          int byte = r * 256 + (((((kk << 2) + (lane >> 4))) ^ (r & 7)) << 4);
          bf16x8 kf = *(const bf16x8*)(smem + byte);
          s = __builtin_amdgcn_mfma_f32_16x16x32_bf16(qf[kk], kf, s, 0, 0, 0);
        }
        sfr[kc] = s;
      }
      // ---- causal mask (scale pre-folded into Q) ----
      const int qbase = Q0 + wave * 16 + ((lane >> 4) << 2);
#pragma unroll
      for (int kc = 0; kc < 2; ++kc) {
        int kidx = kt * 32 + kc * 16 + (lane & 15);
#pragma unroll
        for (int j = 0; j < 4; ++j)
          if (kidx > qbase + j) sfr[kc][j] = -3.0e38f;
      }
      // ---- online softmax (reduce across lane&15 group) ----
      float pr0[4], pr1[4];
#pragma unroll
      for (int j = 0; j < 4; ++j) {
        float mx = fmaxf(sfr[0][j], sfr[1][j]);
#pragma unroll
        for (int msk = 8; msk >= 1; msk >>= 1) mx = fmaxf(mx, __shfl_xor(mx, msk));
        float mnew = fmaxf(mrow[j], mx);
        float alpha = __expf(mrow[j] - mnew);
        float p0 = __expf(sfr[0][j] - mnew);
        float p1 = __expf(sfr[1][j] - mnew);
        float rs = p0 + p1;
#pragma unroll
        for (int msk = 8; msk >= 1; msk >>= 1) rs += __shfl_xor(rs, msk);
        lrow[j] = lrow[j] * alpha + rs;
        mrow[j] = mnew;
#pragma unroll
        for (int d = 0; d < 8; ++d) oacc[d][j] *= alpha;
        pr0[j] = p0; pr1[j] = p1;
      }
      // ---- P -> LDS (per-wave region, swizzled), read back as A-fragment ----
      char* pbase = smem + 16384 + wave * 1024;
#pragma unroll
      for (int j = 0; j < 4; ++j) {
        int q = ((lane >> 4) << 2) + j;
        int k0w = lane & 15;
        int by0 = q * 64 + (((k0w >> 3) ^ (q & 3)) << 4) + ((k0w & 7) << 1);
        *(u16*)(pbase + by0) = f2bf(pr0[j]);
        int k1w = 16 + k0w;
        int by1 = q * 64 + (((k1w >> 3) ^ (q & 3)) << 4) + ((k1w & 7) << 1);
        *(u16*)(pbase + by1) = f2bf(pr1[j]);
      }
      {
        int q = lane & 15;
        bf16x8 pf = *(const bf16x8*)(pbase + q * 64 + (((lane >> 4) ^ (q & 3)) << 4));
        // ---- PV: O[16q x 128d] += P[16x32] @ V[32x128] ----
        int d = (lane & 15);
        int k0 = (lane >> 4) << 3;
#pragma unroll
        for (int dt = 0; dt < 8; ++dt) {
          int dd = (dt << 4) + d;
          int base_v = 8192 + k0 * 256 + ((dd & 7) << 1);
          int c0 = dd >> 3;
          bf16x8 vf;
#pragma unroll
          for (int j = 0; j < 8; ++j)
            vf[j] = *(const __bf16*)(smem + base_v + j * 256 + (((c0 ^ j)) << 4));
          oacc[dt] = __builtin_amdgcn_mfma_f32_16x16x32_bf16(pf, vf, oacc[dt], 0, 0, 0);
        }
      }
    }
    __syncthreads();
  }

  // epilogue: O / l -> Ob (bf16, [4096][2048], col = h*128 + d)
#pragma unroll
  for (int j = 0; j < 4; ++j) {
    int q = Q0 + wave * 16 + ((lane >> 4) << 2) + j;
    float inv = 1.0f / lrow[j];
    u16* op = Ob + (size_t)(brow + q) * 2048 + qcol + (lane & 15);
#pragma unroll
    for (int dt = 0; dt < 8; ++dt) op[dt * 16] = f2bf(oacc[dt][j] * inv);
  }
}

// ---------------- launch ----------------
extern "C" void kernel_launch(void* const* d_in, const int* in_sizes, int n_in,
                              void* d_out, int out_size, void* d_ws, size_t ws_size,
                              hipStream_t stream) {
  const float* x  = (const float*)d_in[0];
  const float* wq = (const float*)d_in[1];
  const float* bq = (const float*)d_in[2];
  const float* wk = (const float*)d_in[3];
  const float* bk = (const float*)d_in[4];
  const float* wv = (const float*)d_in[5];
  const float* bv = (const float*)d_in[6];
  const float* wo = (const float*)d_in[7];
  const float* bo = (const float*)d_in[8];
  // d_in[9] (masked) is analytically causal -> ignored.
  float* out = (float*)d_out;

  u16* wsu = (u16*)d_ws;
  u16* xb      = wsu;                          // 4096x2048 bf16
  u16* wqkvb   = xb + (size_t)4096 * 2048;     // 3072x2048 bf16 (wq|wk|wv)
  u16* wob     = wqkvb + (size_t)3072 * 2048;  // 2048x2048 bf16
  u16* qkv     = wob + (size_t)2048 * 2048;    // 4096x3072 bf16
  float* biascat = (float*)(qkv + (size_t)4096 * 3072);  // 3072 f32
  u16* Ob = xb;  // alias: xb dead after QKV GEMM+rope

  int n4;
  n4 = (4096 * 2048) / 4;
  k_cvt_bf16<<<(n4 + 255) / 256, 256, 0, stream>>>(x, xb, n4);
  n4 = (2048 * 2048) / 4;
  k_cvt_bf16<<<(n4 + 255) / 256, 256, 0, stream>>>(wq, wqkvb, n4);
  n4 = (512 * 2048) / 4;
  k_cvt_bf16<<<(n4 + 255) / 256, 256, 0, stream>>>(wk, wqkvb + (size_t)2048 * 2048, n4);
  k_cvt_bf16<<<(n4 + 255) / 256, 256, 0, stream>>>(wv, wqkvb + (size_t)2560 * 2048, n4);
  n4 = (2048 * 2048) / 4;
  k_cvt_bf16<<<(n4 + 255) / 256, 256, 0, stream>>>(wo, wob, n4);

  hipMemcpyAsync(biascat, bq, 2048 * sizeof(float), hipMemcpyDeviceToDevice, stream);
  hipMemcpyAsync(biascat + 2048, bk, 512 * sizeof(float), hipMemcpyDeviceToDevice, stream);
  hipMemcpyAsync(biascat + 2560, bv, 512 * sizeof(float), hipMemcpyDeviceToDevice, stream);

  // QKV projection: (4096x2048) @ (3072x2048)^T + bias -> bf16 QKV
  k_gemm_bt<0><<<dim3(3072 / 128, 4096 / 128), 256, 0, stream>>>(
      xb, wqkvb, biascat, qkv, 4096, 3072, 2048);

  // RoPE on Q and K (folds 1/sqrt(128) into Q)
  k_rope<<<(4096 * 1280) / 256, 256, 0, stream>>>(qkv);

  // causal GQA flash attention -> Ob bf16 (4096x2048)
  k_attn<<<dim3(2048 / 64, 32), 256, 0, stream>>>(qkv, Ob);

  // output projection: (4096x2048) @ (2048x2048)^T + bo -> f32 d_out
  k_gemm_bt<1><<<dim3(2048 / 128, 4096 / 128), 256, 0, stream>>>(
      Ob, wob, bo, out, 4096, 2048, 2048);
}

// Round 5
// 276.833 us; speedup vs baseline: 1.7164x; 1.7164x over previous
//
#include <hip/hip_runtime.h>

typedef unsigned short u16;
typedef __attribute__((ext_vector_type(4))) float f32x4;
typedef __attribute__((ext_vector_type(8))) __bf16 bf16x8;
typedef __attribute__((ext_vector_type(8))) unsigned short u16x8;

static __device__ __forceinline__ u16 f2bf(float f) {
  unsigned u = __float_as_uint(f);
  u += 0x7FFFu + ((u >> 16) & 1u);
  return (u16)(u >> 16);
}
static __device__ __forceinline__ float bf2f(u16 h) {
  return __uint_as_float(((unsigned)h) << 16);
}

#define GLOAD16(gsrc, ldst)                                                    \
  __builtin_amdgcn_global_load_lds(                                            \
      (const __attribute__((address_space(1))) unsigned int*)(gsrc),           \
      (__attribute__((address_space(3))) unsigned int*)(ldst), 16, 0, 0)

// ---------------- f32 -> bf16 convert (vectorized) ----------------
__global__ void k_cvt_bf16(const float* __restrict__ in, u16* __restrict__ out, int n4) {
  int i = blockIdx.x * blockDim.x + threadIdx.x;
  if (i >= n4) return;
  float4 v = ((const float4*)in)[i];
  ushort4 o;
  o.x = f2bf(v.x); o.y = f2bf(v.y); o.z = f2bf(v.z); o.w = f2bf(v.w);
  ((ushort4*)out)[i] = o;
}

// ---------------- GEMM: C[M,N] = A[M,K] @ Bt[N,K]^T + bias ----------------
// (unchanged — proven correct across rounds 2-4)
template <int OUT_F32>
__global__ __launch_bounds__(256) void k_gemm_bt(const u16* __restrict__ A,
                                                 const u16* __restrict__ Bt,
                                                 const float* __restrict__ bias,
                                                 void* __restrict__ Cv,
                                                 int M, int N, int K) {
  __shared__ __align__(128) char smem[16384];
  const int tid = threadIdx.x;
  const int lane = tid & 63;
  const int wave = tid >> 6;
  const int m0 = blockIdx.y << 7;
  const int n0 = blockIdx.x << 7;
  const int wr = (wave >> 1) << 6;
  const int wc = (wave & 1) << 6;

  f32x4 acc[4][4];
#pragma unroll
  for (int m = 0; m < 4; ++m)
#pragma unroll
    for (int n = 0; n < 4; ++n) acc[m][n] = (f32x4){0.f, 0.f, 0.f, 0.f};

  const int nk = K >> 5;
  for (int kt = 0; kt < nk; ++kt) {
    const int kk0 = kt << 5;
#pragma unroll
    for (int iss = 0; iss < 4; ++iss) {
      int o = tid * 16 + iss * 4096;
      int lo = o & 8191;
      int row = lo >> 6;
      int cs = ((lo >> 4) & 3) ^ (row & 3);
      const u16* src =
          (o >= 8192 ? Bt + (size_t)(n0 + row) * K : A + (size_t)(m0 + row) * K) + kk0 + cs * 8;
      GLOAD16(src, smem + iss * 4096 + wave * 1024);
    }
    __syncthreads();
    bf16x8 af[4], bfr[4];
#pragma unroll
    for (int m = 0; m < 4; ++m) {
      int r = wr + m * 16 + (lane & 15);
      af[m] = *(const bf16x8*)(smem + r * 64 + (((lane >> 4) ^ (r & 3)) << 4));
    }
#pragma unroll
    for (int n = 0; n < 4; ++n) {
      int r = wc + n * 16 + (lane & 15);
      bfr[n] = *(const bf16x8*)(smem + 8192 + r * 64 + (((lane >> 4) ^ (r & 3)) << 4));
    }
#pragma unroll
    for (int m = 0; m < 4; ++m)
#pragma unroll
      for (int n = 0; n < 4; ++n)
        acc[m][n] = __builtin_amdgcn_mfma_f32_16x16x32_bf16(af[m], bfr[n], acc[m][n], 0, 0, 0);
    __syncthreads();
  }

#pragma unroll
  for (int n = 0; n < 4; ++n) {
    int col = n0 + wc + n * 16 + (lane & 15);
    float bsv = bias[col];
#pragma unroll
    for (int m = 0; m < 4; ++m) {
      int rb = m0 + wr + m * 16 + ((lane >> 4) << 2);
#pragma unroll
      for (int j = 0; j < 4; ++j) {
        float v = acc[m][n][j] + bsv;
        if (OUT_F32)
          ((float*)Cv)[(size_t)(rb + j) * N + col] = v;
        else
          ((u16*)Cv)[(size_t)(rb + j) * N + col] = f2bf(v);
      }
    }
  }
}

// ---------------- RoPE (in place on QKV buffer), folds 1/sqrt(DH) into Q ----
__global__ void k_rope(u16* __restrict__ qkv) {
  int t = blockIdx.x * blockDim.x + threadIdx.x;  // 4096*1280 exact
  int row = t / 1280;
  int p = t - row * 1280;
  int head = p >> 6;  // 0..15 Q heads, 16..19 K heads
  int i = p & 63;
  int s = row & 2047;
  int col = head < 16 ? (head << 7) + (i << 1) : 2048 + ((head - 16) << 7) + (i << 1);
  u16* ptr = qkv + (size_t)row * 3072 + col;
  ushort2 xv = *(ushort2*)ptr;
  float xe = bf2f(xv.x), xo = bf2f(xv.y);
  float omega = __expf(-0.21586735f * (float)i);  // exp(-2i/128 * ln 1e6)
  float ang = (float)s * omega;
  float sn, cs;
  sincosf(ang, &sn, &cs);
  float re = xe * cs - xo * sn;
  float ro = xo * cs + xe * sn;
  if (head < 16) { re *= 0.08838834764831845f; ro *= 0.08838834764831845f; }
  ushort2 ov;
  ov.x = f2bf(re); ov.y = f2bf(ro);
  *(ushort2*)ptr = ov;
}

// ---------------- causal GQA flash attention (v2.1) ----------------
// v2 + FIX: explicit lgkmcnt(0) + sched_barrier between the P LDS stores and
// the P ds_read_b128 (cross-lane RAW through differently-typed pointers —
// TBAA lets the scheduler break it; caused post-timing divergence in r4).
__global__ __launch_bounds__(256) void k_attn(const u16* __restrict__ qkv,
                                              u16* __restrict__ Ob) {
  __shared__ __align__(128) char smem[43008];  // K 16384 | Vt 18432 | P 4x2048
  const int tid = threadIdx.x, lane = tid & 63, wave = tid >> 6;
  const int g16 = lane >> 4;   // 16-lane group 0..3
  const int l15 = lane & 15;
  const int bh = blockIdx.x;
  const int Q0 = (31 - blockIdx.y) << 6;  // longest blocks first
  const int b = bh >> 4, h = bh & 15, gq = h >> 2;
  const int brow = b << 11;
  const int qcol = h << 7;
  const int kcol = 2048 + (gq << 7);
  const int vcol = 2560 + (gq << 7);

  // Q A-fragments: row = l15, k(=d) = g16*8 + j per 32-wide chunk kk
  bf16x8 qf[4];
  {
    int qrow = brow + Q0 + wave * 16 + l15;
    const u16* qp = qkv + (size_t)qrow * 3072 + qcol + (g16 << 3);
#pragma unroll
    for (int kk = 0; kk < 4; ++kk) qf[kk] = *(const bf16x8*)(qp + kk * 32);
  }

  f32x4 oacc[8];
#pragma unroll
  for (int d = 0; d < 8; ++d) oacc[d] = (f32x4){0.f, 0.f, 0.f, 0.f};
  float mrow[4], lrow[4];
#pragma unroll
  for (int j = 0; j < 4; ++j) { mrow[j] = -1e30f; lrow[j] = 0.f; }

  const int nkt = (Q0 >> 6) + 1;
  char* const pbase = smem + 34816 + wave * 2048;

  for (int kt = 0; kt < nkt; ++kt) {
    const size_t krowg = (size_t)(brow + (kt << 6));
    // ---- stage K: 64 rows x 256B, chunk swizzle c^(r&7), direct-to-LDS ----
#pragma unroll
    for (int iss = 0; iss < 4; ++iss) {
      int o = iss * 4096 + tid * 16;
      int row = o >> 8;
      int cs = ((o >> 4) & 15) ^ (row & 7);
      const u16* src = qkv + (krowg + row) * 3072 + kcol + cs * 8;
      GLOAD16(src, smem + iss * 4096 + wave * 1024);
    }
    // ---- stage V^T: reg transpose, Vt[d][k] row stride 144B ----
    {
      const u16* vbase = qkv + krowg * 3072 + vcol;
      const int kp = tid & 31;  // k pair -> k = 2kp, 2kp+1
#pragma unroll
      for (int u = 0; u < 2; ++u) {
        int d0 = (((tid >> 5) & 7) + u * 8) << 3;
        const u16* s0 = vbase + (size_t)(kp * 2) * 3072 + d0;
        u16x8 r0 = *(const u16x8*)s0;
        u16x8 r1 = *(const u16x8*)(s0 + 3072);
        char* wb = smem + 16384 + kp * 4;
#pragma unroll
        for (int j = 0; j < 8; ++j) {
          unsigned val = (unsigned)r0[j] | ((unsigned)r1[j] << 16);
          *(unsigned*)(wb + (d0 + j) * 144) = val;
        }
      }
    }
    __syncthreads();

    // ---- QK^T: S[16q x 64k], four 16-col fragments ----
    f32x4 sfr[4];
#pragma unroll
    for (int kc = 0; kc < 4; ++kc) {
      f32x4 s = (f32x4){0.f, 0.f, 0.f, 0.f};
      int r = kc * 16 + l15;
#pragma unroll
      for (int kk = 0; kk < 4; ++kk) {
        int byte = r * 256 + ((((kk << 2) + g16) ^ (r & 7)) << 4);
        bf16x8 kf = *(const bf16x8*)(smem + byte);
        s = __builtin_amdgcn_mfma_f32_16x16x32_bf16(qf[kk], kf, s, 0, 0, 0);
      }
      sfr[kc] = s;
    }
    // ---- causal mask (scale pre-folded into Q) ----
    const int qbase = Q0 + wave * 16 + (g16 << 2);
#pragma unroll
    for (int kc = 0; kc < 4; ++kc) {
      int kidx = (kt << 6) + kc * 16 + l15;
#pragma unroll
      for (int j = 0; j < 4; ++j)
        if (kidx > qbase + j) sfr[kc][j] = -3.0e38f;
    }
    // ---- online softmax (reduce across l15 group) ----
    float pr[4][4];
#pragma unroll
    for (int j = 0; j < 4; ++j) {
      float mx = fmaxf(fmaxf(sfr[0][j], sfr[1][j]), fmaxf(sfr[2][j], sfr[3][j]));
#pragma unroll
      for (int msk = 8; msk >= 1; msk >>= 1) mx = fmaxf(mx, __shfl_xor(mx, msk));
      float mnew = fmaxf(mrow[j], mx);
      float alpha = __expf(mrow[j] - mnew);
      float rs = 0.f;
#pragma unroll
      for (int kc = 0; kc < 4; ++kc) {
        pr[kc][j] = __expf(sfr[kc][j] - mnew);
        rs += pr[kc][j];
      }
#pragma unroll
      for (int msk = 8; msk >= 1; msk >>= 1) rs += __shfl_xor(rs, msk);
      lrow[j] = lrow[j] * alpha + rs;
      mrow[j] = mnew;
#pragma unroll
      for (int d = 0; d < 8; ++d) oacc[d][j] *= alpha;
    }
    // ---- P -> per-wave LDS (16q x 64k, chunk swizzle c^(q&7)) ----
#pragma unroll
    for (int kc = 0; kc < 4; ++kc)
#pragma unroll
      for (int j = 0; j < 4; ++j) {
        int q = (g16 << 2) + j;
        int k = kc * 16 + l15;
        int by = q * 128 + (((k >> 3) ^ (q & 7)) << 4) + ((k & 7) << 1);
        *(u16*)(pbase + by) = f2bf(pr[kc][j]);
      }
    // FIX: order the cross-lane P store->load RAW explicitly. The u16 stores
    // and bf16x8 loads are different TBAA types; without this the scheduler
    // may issue the ds_read before the ds_writes complete (r4 replay races).
    asm volatile("s_waitcnt lgkmcnt(0)" ::: "memory");
    __builtin_amdgcn_sched_barrier(0);
    // ---- PV: O[16q x 128d] += P[16x64] @ V[64x128] ----
#pragma unroll
    for (int ks = 0; ks < 2; ++ks) {
      bf16x8 pf = *(const bf16x8*)(pbase + l15 * 128 +
                                   ((((ks << 2) + g16) ^ (l15 & 7)) << 4));
#pragma unroll
      for (int dt = 0; dt < 8; ++dt) {
        int d = (dt << 4) + l15;
        bf16x8 vf = *(const bf16x8*)(smem + 16384 + d * 144 + (ks << 6) + (g16 << 4));
        oacc[dt] = __builtin_amdgcn_mfma_f32_16x16x32_bf16(pf, vf, oacc[dt], 0, 0, 0);
      }
    }
    __syncthreads();
  }

  // epilogue: O / l -> Ob (bf16, [4096][2048], col = h*128 + d)
#pragma unroll
  for (int j = 0; j < 4; ++j) {
    int q = Q0 + wave * 16 + (g16 << 2) + j;
    float inv = 1.0f / lrow[j];
    u16* op = Ob + (size_t)(brow + q) * 2048 + qcol + l15;
#pragma unroll
    for (int dt = 0; dt < 8; ++dt) op[dt * 16] = f2bf(oacc[dt][j] * inv);
  }
}

// ---------------- launch ----------------
extern "C" void kernel_launch(void* const* d_in, const int* in_sizes, int n_in,
                              void* d_out, int out_size, void* d_ws, size_t ws_size,
                              hipStream_t stream) {
  const float* x  = (const float*)d_in[0];
  const float* wq = (const float*)d_in[1];
  const float* bq = (const float*)d_in[2];
  const float* wk = (const float*)d_in[3];
  const float* bk = (const float*)d_in[4];
  const float* wv = (const float*)d_in[5];
  const float* bv = (const float*)d_in[6];
  const float* wo = (const float*)d_in[7];
  const float* bo = (const float*)d_in[8];
  // d_in[9] (masked) is analytically causal -> ignored.
  float* out = (float*)d_out;

  u16* wsu = (u16*)d_ws;
  u16* xb      = wsu;                          // 4096x2048 bf16
  u16* wqkvb   = xb + (size_t)4096 * 2048;     // 3072x2048 bf16 (wq|wk|wv)
  u16* wob     = wqkvb + (size_t)3072 * 2048;  // 2048x2048 bf16
  u16* qkv     = wob + (size_t)2048 * 2048;    // 4096x3072 bf16
  float* biascat = (float*)(qkv + (size_t)4096 * 3072);  // 3072 f32
  u16* Ob = xb;  // alias: xb dead after QKV GEMM+rope

  int n4;
  n4 = (4096 * 2048) / 4;
  k_cvt_bf16<<<(n4 + 255) / 256, 256, 0, stream>>>(x, xb, n4);
  n4 = (2048 * 2048) / 4;
  k_cvt_bf16<<<(n4 + 255) / 256, 256, 0, stream>>>(wq, wqkvb, n4);
  n4 = (512 * 2048) / 4;
  k_cvt_bf16<<<(n4 + 255) / 256, 256, 0, stream>>>(wk, wqkvb + (size_t)2048 * 2048, n4);
  k_cvt_bf16<<<(n4 + 255) / 256, 256, 0, stream>>>(wv, wqkvb + (size_t)2560 * 2048, n4);
  n4 = (2048 * 2048) / 4;
  k_cvt_bf16<<<(n4 + 255) / 256, 256, 0, stream>>>(wo, wob, n4);

  hipMemcpyAsync(biascat, bq, 2048 * sizeof(float), hipMemcpyDeviceToDevice, stream);
  hipMemcpyAsync(biascat + 2048, bk, 512 * sizeof(float), hipMemcpyDeviceToDevice, stream);
  hipMemcpyAsync(biascat + 2560, bv, 512 * sizeof(float), hipMemcpyDeviceToDevice, stream);

  // QKV projection: (4096x2048) @ (3072x2048)^T + bias -> bf16 QKV
  k_gemm_bt<0><<<dim3(3072 / 128, 4096 / 128), 256, 0, stream>>>(
      xb, wqkvb, biascat, qkv, 4096, 3072, 2048);

  // RoPE on Q and K (folds 1/sqrt(128) into Q)
  k_rope<<<(4096 * 1280) / 256, 256, 0, stream>>>(qkv);

  // causal GQA flash attention -> Ob bf16 (4096x2048)
  k_attn<<<dim3(32, 32), 256, 0, stream>>>(qkv, Ob);

  // output projection: (4096x2048) @ (2048x2048)^T + bo -> f32 d_out
  k_gemm_bt<1><<<dim3(2048 / 128, 4096 / 128), 256, 0, stream>>>(
      Ob, wob, bo, out, 4096, 2048, 2048);
}